// Round 1
// baseline (8073.000 us; speedup 1.0000x reference)
//
#include <hip/hip_runtime.h>
#include <hip/hip_bf16.h>
#include <math.h>

// Problem constants (match reference)
#define DT_     0.1f
#define TAU_M_  10.0f
#define TAU_S_  5.0f
#define NP_     8      // P populations
#define NN_     2048   // N neurons
#define NE_     16     // E edges
#define NB_     4      // B batch
#define NT_     128    // T steps

// Matmul decomposition
#define CH_     16     // split-K chunks over i
#define IL_     128    // rows per chunk (CH_*IL_ == NN_)
#define JT_     2      // j tiles of 1024 columns (256 thr * float4)
#define NEDGE_  17     // 16 recurrent + 1 input projection

__device__ __forceinline__ float sigmoidf_(float x) {
  return 1.0f / (1.0f + expf(-x));
}

__global__ __launch_bounds__(256) void k_init(
    const float* __restrict__ v0, const float* __restrict__ s0,
    const float* __restrict__ s_in0,
    float* __restrict__ v, float* __restrict__ s, float* __restrict__ s_in,
    float* __restrict__ rates, float* __restrict__ errpart) {
  int idx = blockIdx.x * 256 + threadIdx.x;
  if (idx < NE_ * NB_ * NN_) s[idx] = s0[idx];
  if (idx < NP_ * NB_ * NN_) {
    float vv = v0[idx];
    v[idx] = vv;
    rates[idx] = sigmoidf_(vv);
  }
  if (idx < NB_ * NN_) s_in[idx] = s_in0[idx];
  if (idx < 64) errpart[idx] = 0.0f;
}

// Kernel A: split-K matmul. drive_part[ch][e][b][j] = sum_{i in chunk} pre[e,b,i]*W[e,i,j]
__global__ __launch_bounds__(256) void k_stepA(
    const float* __restrict__ W, const float* __restrict__ W_in,
    const float* __restrict__ rates, const float* __restrict__ t_seq,
    const int* __restrict__ src, float* __restrict__ part, int step) {
  const int e   = blockIdx.x;   // 0..16 (16 == input projection)
  const int jt  = blockIdx.y;   // 0..JT_-1
  const int ch  = blockIdx.z;   // 0..CH_-1
  const int tid = threadIdx.x;  // 0..255

  __shared__ float pre[NB_][IL_];

  const int i0 = ch * IL_;
  // Stage pre-activity for this i-chunk: 4 batches x 128 rows
  for (int k = tid; k < NB_ * IL_; k += 256) {
    int b  = k >> 7;       // /128
    int il = k & (IL_ - 1);
    float val;
    if (e == 16) {
      float t = t_seq[b * NT_ + step];
      float phase = (float)(i0 + il) * (6.2831853071795864f / (float)NN_);
      val = 0.5f * (1.0f + sinf(6.2831853071795864f * t * 0.01f + phase));
    } else {
      int sp = src[e];
      val = rates[(sp * NB_ + b) * NN_ + (i0 + il)];
    }
    pre[b][il] = val;
  }
  __syncthreads();

  const float* Wp = (e == 16) ? W_in : (W + (size_t)e * NN_ * NN_);
  const int j = jt * 1024 + tid * 4;

  float acc[NB_][4] = {};
#pragma unroll 4
  for (int il = 0; il < IL_; ++il) {
    const float4 w = *(const float4*)(Wp + (size_t)(i0 + il) * NN_ + j);
#pragma unroll
    for (int b = 0; b < NB_; ++b) {
      float p = pre[b][il];
      acc[b][0] += p * w.x;
      acc[b][1] += p * w.y;
      acc[b][2] += p * w.z;
      acc[b][3] += p * w.w;
    }
  }

#pragma unroll
  for (int b = 0; b < NB_; ++b) {
    float4 o;
    o.x = acc[b][0]; o.y = acc[b][1]; o.z = acc[b][2]; o.w = acc[b][3];
    *(float4*)(part + ((((size_t)ch * NEDGE_ + e) * NB_ + b) * NN_) + j) = o;
  }
}

// Kernel B: reduce partials, synapse + membrane update, outputs.
__global__ __launch_bounds__(256) void k_stepB(
    const float* __restrict__ part, const int* __restrict__ tgt,
    float* __restrict__ v, float* __restrict__ s, float* __restrict__ s_in,
    float* __restrict__ rates, float* __restrict__ errpart,
    float* __restrict__ out, int step) {
  const int idx = blockIdx.x * 256 + threadIdx.x;  // 0..8191 -> (b,n)
  const int b = idx >> 11;
  const int n = idx & (NN_ - 1);

  int tg[NE_];
#pragma unroll
  for (int e = 0; e < NE_; ++e) tg[e] = tgt[e];

  float snew[NE_];
#pragma unroll
  for (int e = 0; e < NE_; ++e) {
    float d = 0.0f;
#pragma unroll
    for (int c = 0; c < CH_; ++c)
      d += part[(((size_t)c * NEDGE_ + e) * NB_ + b) * NN_ + n];
    float sv = s[(e * NB_ + b) * NN_ + n];
    float sn = sv + DT_ * (d - sv * (1.0f / TAU_S_));
    s[(e * NB_ + b) * NN_ + n] = sn;
    snew[e] = sn;
  }

  // input synapse
  float din = 0.0f;
#pragma unroll
  for (int c = 0; c < CH_; ++c)
    din += part[(((size_t)c * NEDGE_ + 16) * NB_ + b) * NN_ + n];
  float siv = s_in[b * NN_ + n];
  float sin_new = siv + DT_ * (din - siv * (1.0f / TAU_S_));
  s_in[b * NN_ + n] = sin_new;

  float errsum = 0.0f;
#pragma unroll
  for (int p = 0; p < NP_; ++p) {
    float S = 0.0f;
#pragma unroll
    for (int e = 0; e < NE_; ++e)
      if (tg[e] == p) S += snew[e];
    if (p == 0) S += sin_new;
    float vv = v[(p * NB_ + b) * NN_ + n];
    float I  = S * (1.0f - vv);     // E_REV = 1, G_MAX = 1
    float dv = (-vv - S * vv + I) * (1.0f / TAU_M_);
    float vn = vv + DT_ * dv;
    v[(p * NB_ + b) * NN_ + n] = vn;
    errsum += fabsf(dv);
    float r = sigmoidf_(vn);
    rates[(p * NB_ + b) * NN_ + n] = r;
    // out layout [B,T,P,N]
    out[(((size_t)b * NT_ + step) * NP_ + p) * NN_ + n] = r;
  }

  // deterministic err accumulation: per-block partial slot
  __shared__ float red[256];
  red[threadIdx.x] = errsum;
  __syncthreads();
  for (int w = 128; w > 0; w >>= 1) {
    if (threadIdx.x < w) red[threadIdx.x] += red[threadIdx.x + w];
    __syncthreads();
  }
  if (threadIdx.x == 0) {
    errpart[blockIdx.x] += red[0] * (DT_ / (float)(NP_ * NB_ * NN_));
  }
}

__global__ void k_final(const float* __restrict__ errpart,
                        float* __restrict__ out_err) {
  if (threadIdx.x == 0) {
    float sum = 0.0f;
    for (int i = 0; i < 32; ++i) sum += errpart[i];
    *out_err = sum;
  }
}

extern "C" void kernel_launch(void* const* d_in, const int* in_sizes, int n_in,
                              void* d_out, int out_size, void* d_ws, size_t ws_size,
                              hipStream_t stream) {
  const float* t_seq = (const float*)d_in[0];   // [B,T]
  const float* W     = (const float*)d_in[1];   // [E,N,N]
  const float* W_in  = (const float*)d_in[2];   // [N,N]
  const float* v0    = (const float*)d_in[3];   // [P,B,N]
  const float* s0    = (const float*)d_in[4];   // [E,B,N]
  const float* s_in0 = (const float*)d_in[5];   // [B,N]
  const int*   src   = (const int*)d_in[6];     // [E]
  const int*   tgt   = (const int*)d_in[7];     // [E]
  float* out = (float*)d_out;                   // [B,T,P,N] + err

  float* ws      = (float*)d_ws;
  float* v       = ws;                    // 65536
  float* s       = v + NP_ * NB_ * NN_;   // 131072
  float* s_in    = s + NE_ * NB_ * NN_;   // 8192
  float* rates   = s_in + NB_ * NN_;      // 65536
  float* errpart = rates + NP_ * NB_ * NN_; // 64 (32 used, padded for alignment)
  float* part    = errpart + 64;          // CH_*17*4*2048 = 2,228,224 floats (~8.9 MB)

  hipLaunchKernelGGL(k_init, dim3(512), dim3(256), 0, stream,
                     v0, s0, s_in0, v, s, s_in, rates, errpart);

  for (int t = 0; t < NT_; ++t) {
    hipLaunchKernelGGL(k_stepA, dim3(NEDGE_, JT_, CH_), dim3(256), 0, stream,
                       W, W_in, rates, t_seq, src, part, t);
    hipLaunchKernelGGL(k_stepB, dim3(32), dim3(256), 0, stream,
                       part, tgt, v, s, s_in, rates, errpart, out, t);
  }

  hipLaunchKernelGGL(k_final, dim3(1), dim3(64), 0, stream,
                     errpart, out + (size_t)NB_ * NT_ * NP_ * NN_);
}

// Round 2
// 4179.776 us; speedup vs baseline: 1.9314x; 1.9314x over previous
//
#include <hip/hip_runtime.h>
#include <hip/hip_bf16.h>
#include <math.h>

// Problem constants (match reference)
#define DT_     0.1f
#define TAU_M_  10.0f
#define TAU_S_  5.0f
#define NP_     8      // P populations
#define NN_     2048   // N neurons
#define NE_     16     // E edges
#define NB_     4      // B batch
#define NT_     128    // T steps

#define CH_     16     // split-K chunks over i
#define IL_     128    // rows per chunk (CH_*IL_ == NN_)
#define NEDGE_  17     // 16 recurrent + 1 input projection

typedef __attribute__((ext_vector_type(8))) _Float16 half8;

template <typename T> struct V8;
template <> struct V8<float>    { typedef float    type __attribute__((ext_vector_type(8))); };
template <> struct V8<_Float16> { typedef _Float16 type __attribute__((ext_vector_type(8))); };

__device__ __forceinline__ float sigmoidf_(float x) {
  return 1.0f / (1.0f + expf(-x));
}

// Convert fp32 weights (W then W_in, concatenated logical [17][N][N]) to fp16.
__global__ __launch_bounds__(256) void k_convert(
    const float* __restrict__ W, const float* __restrict__ W_in,
    _Float16* __restrict__ Wh) {
  size_t idx = ((size_t)blockIdx.x * 256 + threadIdx.x) * 8;
  const size_t lim = (size_t)NE_ * NN_ * NN_;
  const float* src = (idx < lim) ? (W + idx) : (W_in + (idx - lim));
  float4 a = *(const float4*)src;
  float4 b = *(const float4*)(src + 4);
  half8 h;
  h[0] = (_Float16)a.x; h[1] = (_Float16)a.y; h[2] = (_Float16)a.z; h[3] = (_Float16)a.w;
  h[4] = (_Float16)b.x; h[5] = (_Float16)b.y; h[6] = (_Float16)b.z; h[7] = (_Float16)b.w;
  *(half8*)(Wh + idx) = h;
}

__global__ __launch_bounds__(256) void k_init(
    const float* __restrict__ v0, const float* __restrict__ s0,
    const float* __restrict__ s_in0,
    float* __restrict__ v, float* __restrict__ s, float* __restrict__ s_in,
    float* __restrict__ rates, float* __restrict__ errpart) {
  int idx = blockIdx.x * 256 + threadIdx.x;
  if (idx < NE_ * NB_ * NN_) s[idx] = s0[idx];
  if (idx < NP_ * NB_ * NN_) {
    float vv = v0[idx];
    v[idx] = vv;
    rates[idx] = sigmoidf_(vv);
  }
  if (idx < NB_ * NN_) s_in[idx] = s_in0[idx];
  if (idx < 256) errpart[idx] = 0.0f;
}

// Kernel A: split-K matmul. part[ch][e][b][j] = sum_{i in chunk} pre[e,b,i]*W[e,i,j]
template <typename WT>
__global__ __launch_bounds__(256) void k_stepA(
    const WT* __restrict__ Wall, const WT* __restrict__ Win,
    const float* __restrict__ rates, const float* __restrict__ t_seq,
    const int* __restrict__ src, float* __restrict__ part, int step) {
  const int e   = blockIdx.x;   // 0..16 (16 == input projection)
  const int ch  = blockIdx.y;   // 0..CH_-1
  const int tid = threadIdx.x;  // 0..255

  __shared__ float pre[NB_][IL_];
  const int i0 = ch * IL_;

  for (int k = tid; k < NB_ * IL_; k += 256) {
    int b  = k >> 7;
    int il = k & (IL_ - 1);
    float val;
    if (e == 16) {
      float t = t_seq[b * NT_ + step];
      float phase = (float)(i0 + il) * (6.2831853071795864f / (float)NN_);
      val = 0.5f * (1.0f + sinf(0.062831853071795864f * t + phase));
    } else {
      val = rates[(src[e] * NB_ + b) * NN_ + (i0 + il)];
    }
    pre[b][il] = val;
  }
  __syncthreads();

  const WT* Wp = (e == 16) ? Win : (Wall + (size_t)e * NN_ * NN_);
  const int j = tid * 8;

  float acc[NB_][8] = {};
  typedef typename V8<WT>::type vec8;
#pragma unroll 4
  for (int il = 0; il < IL_; ++il) {
    vec8 w = *(const vec8*)(Wp + (size_t)(i0 + il) * NN_ + j);
    float wf[8];
#pragma unroll
    for (int k = 0; k < 8; ++k) wf[k] = (float)w[k];
#pragma unroll
    for (int b = 0; b < NB_; ++b) {
      float p = pre[b][il];
#pragma unroll
      for (int k = 0; k < 8; ++k) acc[b][k] += p * wf[k];
    }
  }

#pragma unroll
  for (int b = 0; b < NB_; ++b) {
    float4 o0 = {acc[b][0], acc[b][1], acc[b][2], acc[b][3]};
    float4 o1 = {acc[b][4], acc[b][5], acc[b][6], acc[b][7]};
    float* dst = part + (((size_t)ch * NEDGE_ + e) * NB_ + b) * NN_ + j;
    *(float4*)dst       = o0;
    *(float4*)(dst + 4) = o1;
  }
}

// Kernel R: reduce split-K partials, exponential synapse update.
// thread per (e, b, n-pair): 17*4*1024 = 69632 threads
__global__ __launch_bounds__(256) void k_stepR(
    const float* __restrict__ part, float* __restrict__ s,
    float* __restrict__ s_in) {
  const int idx = blockIdx.x * 256 + threadIdx.x;
  const int e  = idx >> 12;          // /4096
  const int r  = idx & 4095;
  const int b  = r >> 10;
  const int n  = (r & 1023) * 2;

  float2 acc = {0.0f, 0.0f};
#pragma unroll
  for (int c = 0; c < CH_; ++c) {
    float2 pv = *(const float2*)(part + (((size_t)c * NEDGE_ + e) * NB_ + b) * NN_ + n);
    acc.x += pv.x;
    acc.y += pv.y;
  }
  if (e == 16) {
    float2 sv = *(const float2*)(s_in + b * NN_ + n);
    sv.x += DT_ * (acc.x - sv.x * (1.0f / TAU_S_));
    sv.y += DT_ * (acc.y - sv.y * (1.0f / TAU_S_));
    *(float2*)(s_in + b * NN_ + n) = sv;
  } else {
    float* sp = s + ((size_t)e * NB_ + b) * NN_ + n;
    float2 sv = *(const float2*)sp;
    sv.x += DT_ * (acc.x - sv.x * (1.0f / TAU_S_));
    sv.y += DT_ * (acc.y - sv.y * (1.0f / TAU_S_));
    *(float2*)sp = sv;
  }
}

// Kernel B: segment-sum over edges, membrane update, outputs.
// thread per (p, b, n): 65536 threads, 256 blocks
__global__ __launch_bounds__(256) void k_stepB(
    const float* __restrict__ s, const float* __restrict__ s_in,
    const int* __restrict__ tgt,
    float* __restrict__ v, float* __restrict__ rates,
    float* __restrict__ errpart, float* __restrict__ out, int step) {
  const int idx = blockIdx.x * 256 + threadIdx.x;
  const int p = idx >> 13;
  const int b = (idx >> 11) & (NB_ - 1);
  const int n = idx & (NN_ - 1);

  float S = 0.0f;
#pragma unroll
  for (int e = 0; e < NE_; ++e) {
    if (tgt[e] == p) S += s[((size_t)e * NB_ + b) * NN_ + n];
  }
  if (p == 0) S += s_in[b * NN_ + n];

  float* vp = v + ((size_t)p * NB_ + b) * NN_ + n;
  float vv = *vp;
  float I  = S * (1.0f - vv);      // E_REV=1, G_MAX=1
  float dv = (-vv - S * vv + I) * (1.0f / TAU_M_);
  float vn = vv + DT_ * dv;
  *vp = vn;
  float rr = sigmoidf_(vn);
  rates[((size_t)p * NB_ + b) * NN_ + n] = rr;
  out[(((size_t)b * NT_ + step) * NP_ + p) * NN_ + n] = rr;

  // deterministic per-block err partial
  __shared__ float red[256];
  red[threadIdx.x] = fabsf(dv);
  __syncthreads();
  for (int w = 128; w > 0; w >>= 1) {
    if (threadIdx.x < w) red[threadIdx.x] += red[threadIdx.x + w];
    __syncthreads();
  }
  if (threadIdx.x == 0) {
    errpart[blockIdx.x] += red[0] * (DT_ / (float)(NP_ * NB_ * NN_));
  }
}

__global__ void k_final(const float* __restrict__ errpart,
                        float* __restrict__ out_err) {
  if (threadIdx.x == 0) {
    float sum = 0.0f;
    for (int i = 0; i < 256; ++i) sum += errpart[i];
    *out_err = sum;
  }
}

extern "C" void kernel_launch(void* const* d_in, const int* in_sizes, int n_in,
                              void* d_out, int out_size, void* d_ws, size_t ws_size,
                              hipStream_t stream) {
  const float* t_seq = (const float*)d_in[0];   // [B,T]
  const float* W     = (const float*)d_in[1];   // [E,N,N]
  const float* W_in  = (const float*)d_in[2];   // [N,N]
  const float* v0    = (const float*)d_in[3];   // [P,B,N]
  const float* s0    = (const float*)d_in[4];   // [E,B,N]
  const float* s_in0 = (const float*)d_in[5];   // [B,N]
  const int*   src   = (const int*)d_in[6];     // [E]
  const int*   tgt   = (const int*)d_in[7];     // [E]
  float* out = (float*)d_out;                   // [B,T,P,N] + err

  const size_t WH_ELEMS = (size_t)NEDGE_ * NN_ * NN_;      // 71,303,168 halves
  const size_t PART_F   = (size_t)CH_ * NEDGE_ * NB_ * NN_; // 2,228,224 floats
  const size_t STATE_F  = 65536 + 131072 + 8192 + 65536 + 256;
  const size_t NEED_H   = WH_ELEMS * sizeof(_Float16) + (PART_F + STATE_F) * sizeof(float);
  const bool useHalf = ws_size >= NEED_H;

  _Float16* Wh;
  float* part;
  if (useHalf) {
    Wh   = (_Float16*)d_ws;
    part = (float*)(Wh + WH_ELEMS);
  } else {
    Wh   = nullptr;
    part = (float*)d_ws;
  }
  float* v       = part + PART_F;
  float* s       = v + NP_ * NB_ * NN_;
  float* s_in    = s + NE_ * NB_ * NN_;
  float* rates   = s_in + NB_ * NN_;
  float* errpart = rates + NP_ * NB_ * NN_;

  if (useHalf) {
    hipLaunchKernelGGL(k_convert, dim3((unsigned)(WH_ELEMS / (8 * 256))), dim3(256),
                       0, stream, W, W_in, Wh);
  }
  hipLaunchKernelGGL(k_init, dim3(512), dim3(256), 0, stream,
                     v0, s0, s_in0, v, s, s_in, rates, errpart);

  for (int t = 0; t < NT_; ++t) {
    if (useHalf) {
      hipLaunchKernelGGL(k_stepA<_Float16>, dim3(NEDGE_, CH_), dim3(256), 0, stream,
                         Wh, Wh + (size_t)NE_ * NN_ * NN_, rates, t_seq, src, part, t);
    } else {
      hipLaunchKernelGGL(k_stepA<float>, dim3(NEDGE_, CH_), dim3(256), 0, stream,
                         W, W_in, rates, t_seq, src, part, t);
    }
    hipLaunchKernelGGL(k_stepR, dim3(272), dim3(256), 0, stream, part, s, s_in);
    hipLaunchKernelGGL(k_stepB, dim3(256), dim3(256), 0, stream,
                       s, s_in, tgt, v, rates, errpart, out, t);
  }

  hipLaunchKernelGGL(k_final, dim3(1), dim3(64), 0, stream,
                     errpart, out + (size_t)NB_ * NT_ * NP_ * NN_);
}